// Round 9
// baseline (1428.886 us; speedup 1.0000x reference)
//
#include <hip/hip_runtime.h>
#include <hip/hip_bf16.h>
#include <math.h>

#define D 128
#define NG 512
#define NC 10
#define PAD 96
#define CAP 704
#define BN_EPS 1e-5f

typedef __attribute__((ext_vector_type(8))) short frag_ab;  // 8 bf16 = 4 VGPR
typedef __attribute__((ext_vector_type(4))) float f32x4;

__device__ __forceinline__ ushort f2bf(float v) {
    __hip_bfloat16 h = __float2bfloat16(v);
    union { __hip_bfloat16 h; ushort u; } c;
    c.h = h;
    return c.u;
}
__device__ __forceinline__ float bflo(uint u) { return __uint_as_float(u << 16); }
__device__ __forceinline__ float bfhi(uint u) { return __uint_as_float(u & 0xffff0000u); }
__device__ __forceinline__ uint packbf(float x, float y) {
    return (uint)f2bf(x) | ((uint)f2bf(y) << 16);
}

// ---------------- utility ----------------
__global__ void zero_ints(int* __restrict__ p, int n) {
    int i = blockIdx.x * blockDim.x + threadIdx.x;
    int s = gridDim.x * blockDim.x;
    for (; i < n; i += s) p[i] = 0;
}

// ---------------- edge partition: one atomic pass into 16-node buckets ----------------
__global__ void scatter_bucket(const int* __restrict__ srcs, const int* __restrict__ dsts, int E,
                               int* __restrict__ bcnt, uint* __restrict__ ebuf) {
    int i = blockIdx.x * blockDim.x + threadIdx.x;
    int s = gridDim.x * blockDim.x;
    for (; i < E; i += s) {
        int d = dsts[i];
        int b = d >> 4;
        int pos = atomicAdd(&bcnt[b], 1);
        if (pos < CAP) ebuf[(size_t)b * CAP + pos] = (uint)srcs[i] | ((uint)(d & 15) << 24);
    }
}

// per-bucket LDS counting sort -> pad image + cnt; write only used int4 chunks
__global__ void csr_phaseB(const uint* __restrict__ ebuf, const int* __restrict__ bcnt,
                           int* __restrict__ cnt, int* __restrict__ pad, int N) {
    int b = blockIdx.x;
    int tid = threadIdx.x;  // 256
    int n0 = b << 4;
    __shared__ int lcur[16];
    __shared__ int lcnt2[16];
    __shared__ int lpad[16 * PAD];  // 6 KB
    if (tid < 16) lcur[tid] = tid * PAD;
    __syncthreads();
    int ec = bcnt[b];
    if (ec > CAP) ec = CAP;
    const uint* eb = ebuf + (size_t)b * CAP;
    for (int e = tid; e < ec; e += 256) {
        uint w = eb[e];
        int ld = w >> 24;
        int pos = atomicAdd(&lcur[ld], 1);
        if (pos < ld * PAD + PAD) lpad[pos] = (int)(w & 0x00FFFFFFu);
    }
    __syncthreads();
    int ne = N - n0;
    if (ne > 16) ne = 16;
    if (tid < 16) {
        int c = lcur[tid] - tid * PAD;
        if (c > PAD) c = PAD;
        lcnt2[tid] = c;
    }
    __syncthreads();
    if (tid < ne) cnt[n0 + tid] = lcnt2[tid];
    const int CH = PAD / 4;  // 24 int4 chunks per node
    int4* dst4 = (int4*)(pad + (size_t)n0 * PAD);
    const int4* s4 = (const int4*)lpad;
    for (int i = tid; i < 16 * CH; i += 256) {
        int node = i / CH, ch = i - node * CH;
        if (node < ne && ch * 4 < lcnt2[node]) dst4[node * CH + ch] = s4[node * CH + ch];
    }
}

// gstart via binary search on sorted batch
__global__ void gstart_bsearch(const int* __restrict__ batch, int N, int* __restrict__ gstart) {
    int g = blockIdx.x * blockDim.x + threadIdx.x;
    if (g > NG) return;
    if (g == NG) { gstart[NG] = N; return; }
    int lo = 0, hi = N;
    while (lo < hi) {
        int mid = (lo + hi) >> 1;
        if (batch[mid] < g) lo = mid + 1; else hi = mid;
    }
    gstart[g] = lo;
}

// ---------------- fp32 -> bf16x2 convert (x) ----------------
__global__ void cvt_bf16(const float* __restrict__ in, uint* __restrict__ out, int nPairs) {
    int i = blockIdx.x * blockDim.x + threadIdx.x;
    int s = gridDim.x * blockDim.x;
    const float2* in2 = (const float2*)in;
    for (; i < nPairs; i += s) {
        float2 v = in2[i];
        out[i] = packbf(v.x, v.y);
    }
}

// ---------------- weight prep: Wt[n][k] = bf16(W[k][n]), 10 matrices ----------------
__global__ void prep_w(const float* __restrict__ W1, const float* __restrict__ W2,
                       ushort* __restrict__ Wt) {
    int m = blockIdx.x;
    const float* W = (m < 5) ? (W1 + (size_t)m * D * D) : (W2 + (size_t)(m - 5) * D * D);
    ushort* out = Wt + (size_t)m * D * D;
    __shared__ ushort ws[D * D];
    int tid = threadIdx.x;
    for (int i = tid; i < D * D; i += 256) ws[i] = f2bf(W[i]);
    __syncthreads();
    int n = tid >> 1, kh = (tid & 1) << 6;
    uint* op = (uint*)(out + n * D + kh);
#pragma unroll 8
    for (int j = 0; j < 32; ++j) {
        uint lo = ws[(kh + 2 * j) * D + n];
        uint hi = ws[(kh + 2 * j + 1) * D + n];
        op[j] = lo | (hi << 16);
    }
}

// ---------------- FUSED GIN layer: gather+BN-fold -> LDS -> MLP(2 stages) -> zB ----------------
#define ACC8(V) { s0 += bflo(V.x); s1 += bfhi(V.x); s2 += bflo(V.y); s3 += bfhi(V.y); \
                  s4 += bflo(V.z); s5 += bfhi(V.z); s6 += bflo(V.w); s7 += bfhi(V.w); }

__launch_bounds__(256, 2)
__global__ void gin_fused(const uint4* __restrict__ src4, const float* __restrict__ stats,
                          const float* __restrict__ gamma, const float* __restrict__ beta,
                          float invN, const int* __restrict__ deg, const int* __restrict__ pad,
                          const ushort* __restrict__ w1t, const float* __restrict__ b1,
                          const ushort* __restrict__ w2t, const float* __restrict__ b2,
                          uint* __restrict__ outp, int N) {
    int tid = threadIdx.x;
    int blk = blockIdx.x;
    int m0 = blk * 64;
    __shared__ __align__(16) uint4 zt4[64 * 16];   // 16 KB z-tile (bf16, swizzled)
    __shared__ __align__(16) ushort cs[64 * D];    // 16 KB h-tile / out-tile (swizzled)

    // ======== phase 0: gather + BN-fold (identical math/order to agg_pad) ========
    {
        int grp = tid >> 4;   // 16 groups
        int c16 = tid & 15;   // 16B chunk within row
        int cb = c16 * 8;
        float A[8], B[8];
#pragma unroll
        for (int j = 0; j < 8; ++j) { A[j] = 1.f; B[j] = 0.f; }
        if (stats) {
#pragma unroll
            for (int j = 0; j < 8; ++j) {
                int c = cb + j;
                float m = stats[c] * invN;
                float v = fmaxf(stats[D + c] * invN - m * m, 0.f);
                float r = rsqrtf(v + BN_EPS);
                A[j] = r * gamma[c];
                B[j] = beta[c] - m * A[j];
            }
        }
#pragma unroll
        for (int p = 0; p < 4; ++p) {
            int lr = p * 16 + grp;       // local row 0..63
            int n = m0 + lr;
            uint4 o = {0u, 0u, 0u, 0u};
            if (n < N) {
                float s0 = 0.f, s1 = 0.f, s2 = 0.f, s3 = 0.f, s4 = 0.f, s5 = 0.f, s6 = 0.f, s7 = 0.f;
                {
                    uint4 v = src4[(size_t)n * 16 + c16];
                    ACC8(v);
                }
                const int* cp = pad + (size_t)n * PAD;
                int dg = deg[n];
                if (dg > PAD) dg = PAD;
                int e = 0;
                for (; e + 8 <= dg; e += 8) {
                    int i0 = cp[e], i1 = cp[e + 1], i2 = cp[e + 2], i3 = cp[e + 3];
                    int i4 = cp[e + 4], i5 = cp[e + 5], i6 = cp[e + 6], i7 = cp[e + 7];
                    uint4 v0 = src4[(size_t)i0 * 16 + c16];
                    uint4 v1 = src4[(size_t)i1 * 16 + c16];
                    uint4 v2 = src4[(size_t)i2 * 16 + c16];
                    uint4 v3 = src4[(size_t)i3 * 16 + c16];
                    uint4 v4 = src4[(size_t)i4 * 16 + c16];
                    uint4 v5 = src4[(size_t)i5 * 16 + c16];
                    uint4 v6 = src4[(size_t)i6 * 16 + c16];
                    uint4 v7 = src4[(size_t)i7 * 16 + c16];
                    ACC8(v0); ACC8(v1); ACC8(v2); ACC8(v3);
                    ACC8(v4); ACC8(v5); ACC8(v6); ACC8(v7);
                }
                for (; e < dg; ++e) {
                    uint4 v0 = src4[(size_t)cp[e] * 16 + c16];
                    ACC8(v0);
                }
                float db = (float)(dg + 1);
                o.x = packbf(s0 * A[0] + db * B[0], s1 * A[1] + db * B[1]);
                o.y = packbf(s2 * A[2] + db * B[2], s3 * A[3] + db * B[3]);
                o.z = packbf(s4 * A[4] + db * B[4], s5 * A[5] + db * B[5]);
                o.w = packbf(s6 * A[6] + db * B[6], s7 * A[7] + db * B[7]);
            }
            zt4[lr * 16 + (c16 ^ (lr & 15))] = o;   // swizzled write (16B chunks)
        }
    }
    __syncthreads();

    // ======== phase 1: stage-1 GEMM (A from zt LDS) ========
    int lane = tid & 63;
    int wv = tid >> 6;
    int col = lane & 15;
    int kq = lane >> 4;
    int lrow = wv * 16 + col;    // lrow & 15 == col
    const ushort* ztc = (const ushort*)zt4;

    frag_ab a0 = *(const frag_ab*)(ztc + lrow * D + (((0 << 2) + kq) ^ col) * 8);
    frag_ab a1 = *(const frag_ab*)(ztc + lrow * D + (((1 << 2) + kq) ^ col) * 8);
    frag_ab a2 = *(const frag_ab*)(ztc + lrow * D + (((2 << 2) + kq) ^ col) * 8);
    frag_ab a3 = *(const frag_ab*)(ztc + lrow * D + (((3 << 2) + kq) ^ col) * 8);

    f32x4 acc[8];
#pragma unroll
    for (int n = 0; n < 8; ++n) {
        float bz = b1[n * 16 + col];
        acc[n] = (f32x4){bz, bz, bz, bz};
    }
    const char* wl1 = (const char*)w1t + (size_t)col * 256 + kq * 16;
#pragma unroll
    for (int kc = 0; kc < 4; ++kc) {
        frag_ab av = (kc == 0) ? a0 : (kc == 1) ? a1 : (kc == 2) ? a2 : a3;
#pragma unroll
        for (int n = 0; n < 8; ++n) {
            frag_ab bv = *(const frag_ab*)(wl1 + n * 4096 + kc * 64);
            acc[n] = __builtin_amdgcn_mfma_f32_16x16x32_bf16(av, bv, acc[n], 0, 0, 0);
        }
    }
    // epilogue 1 -> swizzled LDS (cs)
    int rbase = wv * 16 + kq * 4;
#pragma unroll
    for (int n = 0; n < 8; ++n) {
#pragma unroll
        for (int r = 0; r < 4; ++r) {
            int row = rbase + r;
            int colo = n * 16 + col;
            int chunk = (colo >> 3) ^ (row & 15);
            cs[row * D + chunk * 8 + (colo & 7)] = f2bf(fmaxf(acc[n][r], 0.f));
        }
    }
    __syncthreads();

    // ======== phase 2: stage-2 GEMM (A from cs LDS) ========
    frag_ab c0 = *(const frag_ab*)(cs + lrow * D + (((0 << 2) + kq) ^ col) * 8);
    frag_ab c1 = *(const frag_ab*)(cs + lrow * D + (((1 << 2) + kq) ^ col) * 8);
    frag_ab c2 = *(const frag_ab*)(cs + lrow * D + (((2 << 2) + kq) ^ col) * 8);
    frag_ab c3 = *(const frag_ab*)(cs + lrow * D + (((3 << 2) + kq) ^ col) * 8);

#pragma unroll
    for (int n = 0; n < 8; ++n) {
        float bz = b2[n * 16 + col];
        acc[n] = (f32x4){bz, bz, bz, bz};
    }
    const char* wl2 = (const char*)w2t + (size_t)col * 256 + kq * 16;
#pragma unroll
    for (int kc = 0; kc < 4; ++kc) {
        frag_ab av = (kc == 0) ? c0 : (kc == 1) ? c1 : (kc == 2) ? c2 : c3;
#pragma unroll
        for (int n = 0; n < 8; ++n) {
            frag_ab bv = *(const frag_ab*)(wl2 + n * 4096 + kc * 64);
            acc[n] = __builtin_amdgcn_mfma_f32_16x16x32_bf16(av, bv, acc[n], 0, 0, 0);
        }
    }
    __syncthreads();  // all stage-2 LDS reads done before overwrite

    // epilogue 2 -> swizzled LDS
#pragma unroll
    for (int n = 0; n < 8; ++n) {
#pragma unroll
        for (int r = 0; r < 4; ++r) {
            int row = rbase + r;
            int colo = n * 16 + col;
            int chunk = (colo >> 3) ^ (row & 15);
            cs[row * D + chunk * 8 + (colo & 7)] = f2bf(fmaxf(acc[n][r], 0.f));
        }
    }
    __syncthreads();

    // coalesced store (undo swizzle on read)
    const uint4* csv = (const uint4*)cs;
    uint4* og = (uint4*)outp;
#pragma unroll
    for (int p = 0; p < 4; ++p) {
        int idx = p * 256 + tid;
        int row = idx >> 4;
        int j = idx & 15;
        uint4 v = csv[row * 16 + (j ^ (row & 15))];
        if (m0 + row < N) og[(size_t)blk * 1024 + idx] = v;
    }
}

// ---------------- per-graph pooling (+ per-graph sq sums), NO global atomics ----------------
template <int BF16>
__global__ void pool_stats(const void* __restrict__ zptr, const int* __restrict__ gstart,
                           float* __restrict__ pool, float* __restrict__ sq) {
    int g = blockIdx.x;
    int tid = threadIdx.x;  // 256
    int r0 = gstart[g], r1 = gstart[g + 1];
    __shared__ float red[256];
    if (BF16) {
        const uint* z = (const uint*)zptr;
        int uc = tid & 63;
        int qq = tid >> 6;
        float s0 = 0.f, s1 = 0.f, q0 = 0.f, q1 = 0.f;
        for (int r = r0 + qq; r < r1; r += 4) {
            uint u = z[(size_t)r * 64 + uc];
            float lo = bflo(u), hi = bfhi(u);
            s0 += lo; s1 += hi;
            q0 += lo * lo; q1 += hi * hi;
        }
        float S0 = 0.f, S1 = 0.f, Q0 = 0.f, Q1 = 0.f;
        red[tid] = s0; __syncthreads();
        if (qq == 0) S0 = red[uc] + red[uc + 64] + red[uc + 128] + red[uc + 192];
        __syncthreads();
        red[tid] = s1; __syncthreads();
        if (qq == 0) S1 = red[uc] + red[uc + 64] + red[uc + 128] + red[uc + 192];
        __syncthreads();
        red[tid] = q0; __syncthreads();
        if (qq == 0) Q0 = red[uc] + red[uc + 64] + red[uc + 128] + red[uc + 192];
        __syncthreads();
        red[tid] = q1; __syncthreads();
        if (qq == 0) Q1 = red[uc] + red[uc + 64] + red[uc + 128] + red[uc + 192];
        if (qq == 0) {
            pool[g * D + 2 * uc] = S0;
            pool[g * D + 2 * uc + 1] = S1;
            sq[g * D + 2 * uc] = Q0;
            sq[g * D + 2 * uc + 1] = Q1;
        }
    } else {
        const float* z = (const float*)zptr;
        int col = tid & 127;
        int half = tid >> 7;
        float s = 0.f;
        for (int r = r0 + half; r < r1; r += 2) s += z[(size_t)r * D + col];
        red[tid] = s;
        __syncthreads();
        if (half == 0) pool[g * D + col] = red[tid] + red[tid + 128];
    }
}

// ---------------- column stats from per-graph partials: tree, no atomics ----------------
__global__ void col_stats(const float* __restrict__ pool, const float* __restrict__ sq,
                          float* __restrict__ stats) {
    int c = blockIdx.x;     // D
    int tid = threadIdx.x;  // 256
    float s = pool[tid * D + c] + pool[(tid + 256) * D + c];
    float q = sq[tid * D + c] + sq[(tid + 256) * D + c];
    __shared__ float rs[256], rq[256];
    rs[tid] = s; rq[tid] = q;
    __syncthreads();
    for (int off = 128; off > 0; off >>= 1) {
        if (tid < off) { rs[tid] += rs[tid + off]; rq[tid] += rq[tid + off]; }
        __syncthreads();
    }
    if (tid == 0) { stats[c] = rs[0]; stats[D + c] = rq[0]; }
}

// ---------------- graph FC (no stat atomics) ----------------
__global__ void fc_forward(const float* __restrict__ pool, const float* __restrict__ stats,
                           const float* __restrict__ gamma, const float* __restrict__ beta,
                           float invN, const int* __restrict__ gstart, const float* __restrict__ gprev,
                           const float* __restrict__ W, const float* __restrict__ bias,
                           float* __restrict__ y) {
    int g = blockIdx.x;     // NG
    int tid = threadIdx.x;  // D
    __shared__ float u[D];
    float pv = pool[g * D + tid];
    float uv;
    if (stats) {
        float m = stats[tid] * invN;
        float var = fmaxf(stats[D + tid] * invN - m * m, 0.f);
        float rs = rsqrtf(var + BN_EPS);
        float a = rs * gamma[tid];
        float b = beta[tid] - m * a;
        float cntg = (float)(gstart[g + 1] - gstart[g]);
        uv = gprev[g * D + tid] + pv * a + cntg * b;
    } else {
        uv = pv;
    }
    u[tid] = uv;
    __syncthreads();
    float acc = bias[tid];
#pragma unroll 8
    for (int k = 0; k < D; ++k) acc = fmaf(u[k], W[k * D + tid], acc);
    y[g * D + tid] = fmaxf(acc, 0.f);
}

// ---------------- BN over G rows (stats in-kernel, one block per column) ----------------
__global__ void fc_bn2(const float* __restrict__ y, const float* __restrict__ gamma,
                       const float* __restrict__ beta, float* __restrict__ gbuf,
                       float* __restrict__ total, int first) {
    int col = blockIdx.x;   // D
    int tid = threadIdx.x;  // 256
    int i0 = tid * D + col, i1 = (tid + 256) * D + col;
    float v0 = y[i0], v1 = y[i1];
    __shared__ float rs[256], rq[256];
    rs[tid] = v0 + v1;
    rq[tid] = v0 * v0 + v1 * v1;
    __syncthreads();
    for (int off = 128; off > 0; off >>= 1) {
        if (tid < off) { rs[tid] += rs[tid + off]; rq[tid] += rq[tid + off]; }
        __syncthreads();
    }
    __shared__ float ab[2];
    if (tid == 0) {
        const float invG = 1.f / NG;
        float m = rs[0] * invG;
        float var = fmaxf(rq[0] * invG - m * m, 0.f);
        float a = rsqrtf(var + BN_EPS) * gamma[col];
        ab[0] = a;
        ab[1] = beta[col] - m * a;
    }
    __syncthreads();
    float a = ab[0], b = ab[1];
    float g0 = v0 * a + b, g1 = v1 * a + b;
    gbuf[i0] = g0;
    gbuf[i1] = g1;
    if (first) { total[i0] = g0; total[i1] = g1; }
    else { total[i0] += g0; total[i1] += g1; }
}

// ---------------- final classifier + log_softmax ----------------
__global__ void final_logits(const float* __restrict__ total, const float* __restrict__ linW,
                             const float* __restrict__ linb, float* __restrict__ out) {
    int g = blockIdx.x;
    int tid = threadIdx.x;  // D
    __shared__ float t[D];
    __shared__ float lg[12];
    t[tid] = total[g * D + tid];
    __syncthreads();
    if (tid < NC) {
        float a = linb[tid];
        for (int k = 0; k < D; ++k) a = fmaf(t[k], linW[k * NC + tid], a);
        lg[tid] = a;
    }
    __syncthreads();
    if (tid == 0) {
        float mx = lg[0];
        for (int c = 1; c < NC; ++c) mx = fmaxf(mx, lg[c]);
        float se = 0.f;
        for (int c = 0; c < NC; ++c) se += expf(lg[c] - mx);
        lg[10] = mx + logf(se);
    }
    __syncthreads();
    if (tid < NC) out[g * NC + tid] = lg[tid] - lg[10];
}

// ---------------- host ----------------
extern "C" void kernel_launch(void* const* d_in, const int* in_sizes, int n_in,
                              void* d_out, int out_size, void* d_ws, size_t ws_size,
                              hipStream_t stream) {
    const float* x = (const float*)d_in[0];
    const int* edge = (const int*)d_in[1];
    const int* batch = (const int*)d_in[2];
    const float* convW1 = (const float*)d_in[3];
    const float* convb1 = (const float*)d_in[4];
    const float* convW2 = (const float*)d_in[5];
    const float* convb2 = (const float*)d_in[6];
    const float* convgamma = (const float*)d_in[7];
    const float* convbeta = (const float*)d_in[8];
    const float* fc1W = (const float*)d_in[9];
    const float* fc1b = (const float*)d_in[10];
    const float* fc1gamma = (const float*)d_in[11];
    const float* fc1beta = (const float*)d_in[12];
    const float* fc2W = (const float*)d_in[13];
    const float* fc2b = (const float*)d_in[14];
    const float* fc2gamma = (const float*)d_in[15];
    const float* fc2beta = (const float*)d_in[16];
    const float* linW = (const float*)d_in[17];
    const float* linb = (const float*)d_in[18];

    const int N = in_sizes[0] / D;
    const int E = in_sizes[1] / 2;
    const int* srcs = edge;
    const int* dsts = edge + E;
    const float invN = 1.f / (float)N;
    const int NBUK = (N + 15) >> 4;  // 16-node buckets

    char* p = (char*)d_ws;
    auto alloc = [&](size_t bytes) -> void* {
        void* r = (void*)p;
        p += (bytes + 255) & ~(size_t)255;
        return r;
    };
    uint* xb = (uint*)alloc((size_t)N * 64 * 4);   // bf16 x
    uint* zA = (uint*)alloc((size_t)N * 64 * 4);   // layer output ping
    uint* zB = (uint*)alloc((size_t)N * 64 * 4);   // layer output pong; aliases ebuf pre-loop
    ushort* wt = (ushort*)alloc((size_t)10 * D * D * 2);
    int* pad = (int*)alloc((size_t)N * PAD * 4);   // padded CSR
    int* cnt = (int*)alloc((size_t)N * 4);
    int* gstart = (int*)alloc((size_t)(NG + 1) * 4);
    int* bcnt = (int*)alloc((size_t)NBUK * 4);
    float* stats_all = (float*)alloc((size_t)5 * 2 * D * 4);
    float* pool = (float*)alloc((size_t)NG * D * 4);
    float* sqbuf = (float*)alloc((size_t)NG * D * 4);
    float* ybuf = (float*)alloc((size_t)NG * D * 4);
    float* gbuf = (float*)alloc((size_t)NG * D * 4);
    float* total = (float*)alloc((size_t)NG * D * 4);

    uint* ebuf = zB;  // NBUK*CAP*4 = 17.6 MB <= N*256B; dead before first layer-1 output (zA)

    // ---- preprocessing ----
    zero_ints<<<(NBUK + 255) / 256, 256, 0, stream>>>(bcnt, NBUK);
    gstart_bsearch<<<3, 256, 0, stream>>>(batch, N, gstart);
    scatter_bucket<<<2048, 256, 0, stream>>>(srcs, dsts, E, bcnt, ebuf);
    cvt_bf16<<<2048, 256, 0, stream>>>(x, xb, N * 64);
    prep_w<<<10, 256, 0, stream>>>(convW1, convW2, wt);
    csr_phaseB<<<NBUK, 256, 0, stream>>>(ebuf, bcnt, cnt, pad, N);

    // ---- g0 path (exact fp32 pooling of x) ----
    pool_stats<0><<<NG, 256, 0, stream>>>(x, gstart, pool, nullptr);
    fc_forward<<<NG, D, 0, stream>>>(pool, nullptr, nullptr, nullptr, 0.f, nullptr, nullptr,
                                     fc1W, fc1b, ybuf);
    fc_bn2<<<D, 256, 0, stream>>>(ybuf, fc1gamma, fc1beta, gbuf, total, 1);

    // ---- 5 GIN layers (fused node path) ----
    const uint* src = xb;
    uint* dst = zA;                 // layer 0 writes zA (ebuf in zB still live until here? no:
                                    // ebuf consumed by csr_phaseB before any layer runs)
    const int fgrid = (N + 63) / 64;
    for (int i = 0; i < 5; ++i) {
        const float* st = (i == 0) ? nullptr : (stats_all + (size_t)(i - 1) * 2 * D);
        const float* ga = (i == 0) ? nullptr : (convgamma + (size_t)(i - 1) * D);
        const float* be = (i == 0) ? nullptr : (convbeta + (size_t)(i - 1) * D);
        gin_fused<<<fgrid, 256, 0, stream>>>((const uint4*)src, st, ga, be, invN, cnt, pad,
                                             wt + (size_t)i * D * D, convb1 + (size_t)i * D,
                                             wt + (size_t)(5 + i) * D * D, convb2 + (size_t)i * D,
                                             dst, N);
        float* st_i = stats_all + (size_t)i * 2 * D;
        pool_stats<1><<<NG, 256, 0, stream>>>(dst, gstart, pool, sqbuf);
        col_stats<<<D, 256, 0, stream>>>(pool, sqbuf, st_i);
        fc_forward<<<NG, D, 0, stream>>>(pool, st_i,
                                         convgamma + (size_t)i * D, convbeta + (size_t)i * D,
                                         invN, gstart, gbuf, fc2W, fc2b, ybuf);
        fc_bn2<<<D, 256, 0, stream>>>(ybuf, fc2gamma, fc2beta, gbuf, total, 0);
        src = dst;
        dst = (dst == zA) ? zB : zA;
    }

    // ---- classifier ----
    final_logits<<<NG, D, 0, stream>>>(total, linW, linb, (float*)d_out);
}

// Round 11
// 1327.092 us; speedup vs baseline: 1.0767x; 1.0767x over previous
//
#include <hip/hip_runtime.h>
#include <hip/hip_bf16.h>
#include <math.h>

#define D 128
#define NG 512
#define NC 10
#define PAD 96
#define CAP 704
#define BN_EPS 1e-5f

typedef __attribute__((ext_vector_type(8))) short frag_ab;  // 8 bf16 = 4 VGPR
typedef __attribute__((ext_vector_type(4))) float f32x4;

__device__ __forceinline__ ushort f2bf(float v) {
    __hip_bfloat16 h = __float2bfloat16(v);
    union { __hip_bfloat16 h; ushort u; } c;
    c.h = h;
    return c.u;
}
__device__ __forceinline__ float bflo(uint u) { return __uint_as_float(u << 16); }
__device__ __forceinline__ float bfhi(uint u) { return __uint_as_float(u & 0xffff0000u); }
__device__ __forceinline__ uint packbf(float x, float y) {
    return (uint)f2bf(x) | ((uint)f2bf(y) << 16);
}

// ---------------- utility ----------------
__global__ void zero_ints(int* __restrict__ p, int n) {
    int i = blockIdx.x * blockDim.x + threadIdx.x;
    int s = gridDim.x * blockDim.x;
    for (; i < n; i += s) p[i] = 0;
}

// ---------------- edge partition: one atomic pass into 16-node buckets ----------------
__global__ void scatter_bucket(const int* __restrict__ srcs, const int* __restrict__ dsts, int E,
                               int* __restrict__ bcnt, uint* __restrict__ ebuf) {
    int i = blockIdx.x * blockDim.x + threadIdx.x;
    int s = gridDim.x * blockDim.x;
    for (; i < E; i += s) {
        int d = dsts[i];
        int b = d >> 4;
        int pos = atomicAdd(&bcnt[b], 1);
        if (pos < CAP) ebuf[(size_t)b * CAP + pos] = (uint)srcs[i] | ((uint)(d & 15) << 24);
    }
}

// per-bucket LDS counting sort -> pad image + cnt; write only used int4 chunks
__global__ void csr_phaseB(const uint* __restrict__ ebuf, const int* __restrict__ bcnt,
                           int* __restrict__ cnt, int* __restrict__ pad, int N) {
    int b = blockIdx.x;
    int tid = threadIdx.x;  // 256
    int n0 = b << 4;
    __shared__ int lcur[16];
    __shared__ int lcnt2[16];
    __shared__ int lpad[16 * PAD];  // 6 KB
    if (tid < 16) lcur[tid] = tid * PAD;
    __syncthreads();
    int ec = bcnt[b];
    if (ec > CAP) ec = CAP;
    const uint* eb = ebuf + (size_t)b * CAP;
    for (int e = tid; e < ec; e += 256) {
        uint w = eb[e];
        int ld = w >> 24;
        int pos = atomicAdd(&lcur[ld], 1);
        if (pos < ld * PAD + PAD) lpad[pos] = (int)(w & 0x00FFFFFFu);
    }
    __syncthreads();
    int ne = N - n0;
    if (ne > 16) ne = 16;
    if (tid < 16) {
        int c = lcur[tid] - tid * PAD;
        if (c > PAD) c = PAD;
        lcnt2[tid] = c;
    }
    __syncthreads();
    if (tid < ne) cnt[n0 + tid] = lcnt2[tid];
    const int CH = PAD / 4;  // 24 int4 chunks per node
    int4* dst4 = (int4*)(pad + (size_t)n0 * PAD);
    const int4* s4 = (const int4*)lpad;
    for (int i = tid; i < 16 * CH; i += 256) {
        int node = i / CH, ch = i - node * CH;
        if (node < ne && ch * 4 < lcnt2[node]) dst4[node * CH + ch] = s4[node * CH + ch];
    }
}

// gstart via binary search on sorted batch
__global__ void gstart_bsearch(const int* __restrict__ batch, int N, int* __restrict__ gstart) {
    int g = blockIdx.x * blockDim.x + threadIdx.x;
    if (g > NG) return;
    if (g == NG) { gstart[NG] = N; return; }
    int lo = 0, hi = N;
    while (lo < hi) {
        int mid = (lo + hi) >> 1;
        if (batch[mid] < g) lo = mid + 1; else hi = mid;
    }
    gstart[g] = lo;
}

// ---------------- fp32 -> bf16x2 convert (x) ----------------
__global__ void cvt_bf16(const float* __restrict__ in, uint* __restrict__ out, int nPairs) {
    int i = blockIdx.x * blockDim.x + threadIdx.x;
    int s = gridDim.x * blockDim.x;
    const float2* in2 = (const float2*)in;
    for (; i < nPairs; i += s) {
        float2 v = in2[i];
        out[i] = packbf(v.x, v.y);
    }
}

// ---------------- weight prep: Wt[n][k] = bf16(W[k][n]), 10 matrices ----------------
__global__ void prep_w(const float* __restrict__ W1, const float* __restrict__ W2,
                       ushort* __restrict__ Wt) {
    int m = blockIdx.x;
    const float* W = (m < 5) ? (W1 + (size_t)m * D * D) : (W2 + (size_t)(m - 5) * D * D);
    ushort* out = Wt + (size_t)m * D * D;
    __shared__ ushort ws[D * D];
    int tid = threadIdx.x;
    for (int i = tid; i < D * D; i += 256) ws[i] = f2bf(W[i]);
    __syncthreads();
    int n = tid >> 1, kh = (tid & 1) << 6;
    uint* op = (uint*)(out + n * D + kh);
#pragma unroll 8
    for (int j = 0; j < 32; ++j) {
        uint lo = ws[(kh + 2 * j) * D + n];
        uint hi = ws[(kh + 2 * j + 1) * D + n];
        op[j] = lo | (hi << 16);
    }
}

// ---------------- FUSED GIN layer: gather+BN-fold -> LDS -> MLP(2 stages) ----------------
// Single 16 KB LDS tile, reused across phases (z-tile consumed into regs before overwrite).
#define ACC8(V) { s0 += bflo(V.x); s1 += bfhi(V.x); s2 += bflo(V.y); s3 += bfhi(V.y); \
                  s4 += bflo(V.z); s5 += bfhi(V.z); s6 += bflo(V.w); s7 += bfhi(V.w); }

__launch_bounds__(256, 4)
__global__ void gin_fused(const uint4* __restrict__ src4, const float* __restrict__ stats,
                          const float* __restrict__ gamma, const float* __restrict__ beta,
                          float invN, const int* __restrict__ deg, const int* __restrict__ pad,
                          const ushort* __restrict__ w1t, const float* __restrict__ b1,
                          const ushort* __restrict__ w2t, const float* __restrict__ b2,
                          uint* __restrict__ outp, int N) {
    int tid = threadIdx.x;
    int blk = blockIdx.x;
    int m0 = blk * 64;
    __shared__ __align__(16) uint4 tile4[64 * 16];   // 16 KB, reused: z-tile then h/out-tile
    ushort* cs = (ushort*)tile4;

    // ======== phase 0: gather + BN-fold (identical math/order to agg_pad) ========
    {
        int grp = tid >> 4;   // 16 groups
        int c16 = tid & 15;   // 16B chunk within row
        int cb = c16 * 8;
        float A[8], B[8];
#pragma unroll
        for (int j = 0; j < 8; ++j) { A[j] = 1.f; B[j] = 0.f; }
        if (stats) {
#pragma unroll
            for (int j = 0; j < 8; ++j) {
                int c = cb + j;
                float m = stats[c] * invN;
                float v = fmaxf(stats[D + c] * invN - m * m, 0.f);
                float r = rsqrtf(v + BN_EPS);
                A[j] = r * gamma[c];
                B[j] = beta[c] - m * A[j];
            }
        }
#pragma unroll
        for (int p = 0; p < 4; ++p) {
            int lr = p * 16 + grp;       // local row 0..63
            int n = m0 + lr;
            uint4 o = {0u, 0u, 0u, 0u};
            if (n < N) {
                float s0 = 0.f, s1 = 0.f, s2 = 0.f, s3 = 0.f, s4 = 0.f, s5 = 0.f, s6 = 0.f, s7 = 0.f;
                {
                    uint4 v = src4[(size_t)n * 16 + c16];
                    ACC8(v);
                }
                const int* cp = pad + (size_t)n * PAD;
                int dg = deg[n];
                if (dg > PAD) dg = PAD;
                int e = 0;
                for (; e + 8 <= dg; e += 8) {
                    int i0 = cp[e], i1 = cp[e + 1], i2 = cp[e + 2], i3 = cp[e + 3];
                    int i4 = cp[e + 4], i5 = cp[e + 5], i6 = cp[e + 6], i7 = cp[e + 7];
                    uint4 v0 = src4[(size_t)i0 * 16 + c16];
                    uint4 v1 = src4[(size_t)i1 * 16 + c16];
                    uint4 v2 = src4[(size_t)i2 * 16 + c16];
                    uint4 v3 = src4[(size_t)i3 * 16 + c16];
                    uint4 v4 = src4[(size_t)i4 * 16 + c16];
                    uint4 v5 = src4[(size_t)i5 * 16 + c16];
                    uint4 v6 = src4[(size_t)i6 * 16 + c16];
                    uint4 v7 = src4[(size_t)i7 * 16 + c16];
                    ACC8(v0); ACC8(v1); ACC8(v2); ACC8(v3);
                    ACC8(v4); ACC8(v5); ACC8(v6); ACC8(v7);
                }
                for (; e < dg; ++e) {
                    uint4 v0 = src4[(size_t)cp[e] * 16 + c16];
                    ACC8(v0);
                }
                float db = (float)(dg + 1);
                o.x = packbf(s0 * A[0] + db * B[0], s1 * A[1] + db * B[1]);
                o.y = packbf(s2 * A[2] + db * B[2], s3 * A[3] + db * B[3]);
                o.z = packbf(s4 * A[4] + db * B[4], s5 * A[5] + db * B[5]);
                o.w = packbf(s6 * A[6] + db * B[6], s7 * A[7] + db * B[7]);
            }
            tile4[lr * 16 + (c16 ^ (lr & 15))] = o;   // swizzled write (16B chunks)
        }
    }
    __syncthreads();

    // ======== phase 1: stage-1 GEMM (A frags from tile, then tile is reused) ========
    int lane = tid & 63;
    int wv = tid >> 6;
    int col = lane & 15;
    int kq = lane >> 4;
    int lrow = wv * 16 + col;    // lrow & 15 == col
    const ushort* ztc = (const ushort*)tile4;

    frag_ab a0 = *(const frag_ab*)(ztc + lrow * D + (((0 << 2) + kq) ^ col) * 8);
    frag_ab a1 = *(const frag_ab*)(ztc + lrow * D + (((1 << 2) + kq) ^ col) * 8);
    frag_ab a2 = *(const frag_ab*)(ztc + lrow * D + (((2 << 2) + kq) ^ col) * 8);
    frag_ab a3 = *(const frag_ab*)(ztc + lrow * D + (((3 << 2) + kq) ^ col) * 8);
    __syncthreads();   // all z-tile reads complete before cs overwrites the same LDS

    f32x4 acc[8];
#pragma unroll
    for (int n = 0; n < 8; ++n) {
        float bz = b1[n * 16 + col];
        acc[n] = (f32x4){bz, bz, bz, bz};
    }
    const char* wl1 = (const char*)w1t + (size_t)col * 256 + kq * 16;
#pragma unroll
    for (int kc = 0; kc < 4; ++kc) {
        frag_ab av = (kc == 0) ? a0 : (kc == 1) ? a1 : (kc == 2) ? a2 : a3;
#pragma unroll
        for (int n = 0; n < 8; ++n) {
            frag_ab bv = *(const frag_ab*)(wl1 + n * 4096 + kc * 64);
            acc[n] = __builtin_amdgcn_mfma_f32_16x16x32_bf16(av, bv, acc[n], 0, 0, 0);
        }
    }
    // epilogue 1 -> swizzled LDS (cs, same buffer)
    int rbase = wv * 16 + kq * 4;
#pragma unroll
    for (int n = 0; n < 8; ++n) {
#pragma unroll
        for (int r = 0; r < 4; ++r) {
            int row = rbase + r;
            int colo = n * 16 + col;
            int chunk = (colo >> 3) ^ (row & 15);
            cs[row * D + chunk * 8 + (colo & 7)] = f2bf(fmaxf(acc[n][r], 0.f));
        }
    }
    __syncthreads();

    // ======== phase 2: stage-2 GEMM (A from cs) ========
    frag_ab c0 = *(const frag_ab*)(cs + lrow * D + (((0 << 2) + kq) ^ col) * 8);
    frag_ab c1 = *(const frag_ab*)(cs + lrow * D + (((1 << 2) + kq) ^ col) * 8);
    frag_ab c2 = *(const frag_ab*)(cs + lrow * D + (((2 << 2) + kq) ^ col) * 8);
    frag_ab c3 = *(const frag_ab*)(cs + lrow * D + (((3 << 2) + kq) ^ col) * 8);

#pragma unroll
    for (int n = 0; n < 8; ++n) {
        float bz = b2[n * 16 + col];
        acc[n] = (f32x4){bz, bz, bz, bz};
    }
    const char* wl2 = (const char*)w2t + (size_t)col * 256 + kq * 16;
#pragma unroll
    for (int kc = 0; kc < 4; ++kc) {
        frag_ab av = (kc == 0) ? c0 : (kc == 1) ? c1 : (kc == 2) ? c2 : c3;
#pragma unroll
        for (int n = 0; n < 8; ++n) {
            frag_ab bv = *(const frag_ab*)(wl2 + n * 4096 + kc * 64);
            acc[n] = __builtin_amdgcn_mfma_f32_16x16x32_bf16(av, bv, acc[n], 0, 0, 0);
        }
    }
    __syncthreads();  // all stage-2 LDS reads done before overwrite

    // epilogue 2 -> swizzled LDS
#pragma unroll
    for (int n = 0; n < 8; ++n) {
#pragma unroll
        for (int r = 0; r < 4; ++r) {
            int row = rbase + r;
            int colo = n * 16 + col;
            int chunk = (colo >> 3) ^ (row & 15);
            cs[row * D + chunk * 8 + (colo & 7)] = f2bf(fmaxf(acc[n][r], 0.f));
        }
    }
    __syncthreads();

    // coalesced store (undo swizzle on read)
    const uint4* csv = (const uint4*)cs;
    uint4* og = (uint4*)outp;
#pragma unroll
    for (int p = 0; p < 4; ++p) {
        int idx = p * 256 + tid;
        int row = idx >> 4;
        int j = idx & 15;
        uint4 v = csv[row * 16 + (j ^ (row & 15))];
        if (m0 + row < N) og[(size_t)blk * 1024 + idx] = v;
    }
}

// ---------------- per-graph pooling (+ per-graph sq sums), NO global atomics ----------------
template <int BF16>
__global__ void pool_stats(const void* __restrict__ zptr, const int* __restrict__ gstart,
                           float* __restrict__ pool, float* __restrict__ sq) {
    int g = blockIdx.x;
    int tid = threadIdx.x;  // 256
    int r0 = gstart[g], r1 = gstart[g + 1];
    __shared__ float red[256];
    if (BF16) {
        const uint* z = (const uint*)zptr;
        int uc = tid & 63;
        int qq = tid >> 6;
        float s0 = 0.f, s1 = 0.f, q0 = 0.f, q1 = 0.f;
        for (int r = r0 + qq; r < r1; r += 4) {
            uint u = z[(size_t)r * 64 + uc];
            float lo = bflo(u), hi = bfhi(u);
            s0 += lo; s1 += hi;
            q0 += lo * lo; q1 += hi * hi;
        }
        float S0 = 0.f, S1 = 0.f, Q0 = 0.f, Q1 = 0.f;
        red[tid] = s0; __syncthreads();
        if (qq == 0) S0 = red[uc] + red[uc + 64] + red[uc + 128] + red[uc + 192];
        __syncthreads();
        red[tid] = s1; __syncthreads();
        if (qq == 0) S1 = red[uc] + red[uc + 64] + red[uc + 128] + red[uc + 192];
        __syncthreads();
        red[tid] = q0; __syncthreads();
        if (qq == 0) Q0 = red[uc] + red[uc + 64] + red[uc + 128] + red[uc + 192];
        __syncthreads();
        red[tid] = q1; __syncthreads();
        if (qq == 0) Q1 = red[uc] + red[uc + 64] + red[uc + 128] + red[uc + 192];
        if (qq == 0) {
            pool[g * D + 2 * uc] = S0;
            pool[g * D + 2 * uc + 1] = S1;
            sq[g * D + 2 * uc] = Q0;
            sq[g * D + 2 * uc + 1] = Q1;
        }
    } else {
        const float* z = (const float*)zptr;
        int col = tid & 127;
        int half = tid >> 7;
        float s = 0.f;
        for (int r = r0 + half; r < r1; r += 2) s += z[(size_t)r * D + col];
        red[tid] = s;
        __syncthreads();
        if (half == 0) pool[g * D + col] = red[tid] + red[tid + 128];
    }
}

// ---------------- column stats from per-graph partials: tree, no atomics ----------------
__global__ void col_stats(const float* __restrict__ pool, const float* __restrict__ sq,
                          float* __restrict__ stats) {
    int c = blockIdx.x;     // D
    int tid = threadIdx.x;  // 256
    float s = pool[tid * D + c] + pool[(tid + 256) * D + c];
    float q = sq[tid * D + c] + sq[(tid + 256) * D + c];
    __shared__ float rs[256], rq[256];
    rs[tid] = s; rq[tid] = q;
    __syncthreads();
    for (int off = 128; off > 0; off >>= 1) {
        if (tid < off) { rs[tid] += rs[tid + off]; rq[tid] += rq[tid + off]; }
        __syncthreads();
    }
    if (tid == 0) { stats[c] = rs[0]; stats[D + c] = rq[0]; }
}

// ---------------- graph FC (no stat atomics) ----------------
__global__ void fc_forward(const float* __restrict__ pool, const float* __restrict__ stats,
                           const float* __restrict__ gamma, const float* __restrict__ beta,
                           float invN, const int* __restrict__ gstart, const float* __restrict__ gprev,
                           const float* __restrict__ W, const float* __restrict__ bias,
                           float* __restrict__ y) {
    int g = blockIdx.x;     // NG
    int tid = threadIdx.x;  // D
    __shared__ float u[D];
    float pv = pool[g * D + tid];
    float uv;
    if (stats) {
        float m = stats[tid] * invN;
        float var = fmaxf(stats[D + tid] * invN - m * m, 0.f);
        float rs = rsqrtf(var + BN_EPS);
        float a = rs * gamma[tid];
        float b = beta[tid] - m * a;
        float cntg = (float)(gstart[g + 1] - gstart[g]);
        uv = gprev[g * D + tid] + pv * a + cntg * b;
    } else {
        uv = pv;
    }
    u[tid] = uv;
    __syncthreads();
    float acc = bias[tid];
#pragma unroll 8
    for (int k = 0; k < D; ++k) acc = fmaf(u[k], W[k * D + tid], acc);
    y[g * D + tid] = fmaxf(acc, 0.f);
}

// ---------------- BN over G rows (stats in-kernel, one block per column) ----------------
__global__ void fc_bn2(const float* __restrict__ y, const float* __restrict__ gamma,
                       const float* __restrict__ beta, float* __restrict__ gbuf,
                       float* __restrict__ total, int first) {
    int col = blockIdx.x;   // D
    int tid = threadIdx.x;  // 256
    int i0 = tid * D + col, i1 = (tid + 256) * D + col;
    float v0 = y[i0], v1 = y[i1];
    __shared__ float rs[256], rq[256];
    rs[tid] = v0 + v1;
    rq[tid] = v0 * v0 + v1 * v1;
    __syncthreads();
    for (int off = 128; off > 0; off >>= 1) {
        if (tid < off) { rs[tid] += rs[tid + off]; rq[tid] += rq[tid + off]; }
        __syncthreads();
    }
    __shared__ float ab[2];
    if (tid == 0) {
        const float invG = 1.f / NG;
        float m = rs[0] * invG;
        float var = fmaxf(rq[0] * invG - m * m, 0.f);
        float a = rsqrtf(var + BN_EPS) * gamma[col];
        ab[0] = a;
        ab[1] = beta[col] - m * a;
    }
    __syncthreads();
    float a = ab[0], b = ab[1];
    float g0 = v0 * a + b, g1 = v1 * a + b;
    gbuf[i0] = g0;
    gbuf[i1] = g1;
    if (first) { total[i0] = g0; total[i1] = g1; }
    else { total[i0] += g0; total[i1] += g1; }
}

// ---------------- final classifier + log_softmax ----------------
__global__ void final_logits(const float* __restrict__ total, const float* __restrict__ linW,
                             const float* __restrict__ linb, float* __restrict__ out) {
    int g = blockIdx.x;
    int tid = threadIdx.x;  // D
    __shared__ float t[D];
    __shared__ float lg[12];
    t[tid] = total[g * D + tid];
    __syncthreads();
    if (tid < NC) {
        float a = linb[tid];
        for (int k = 0; k < D; ++k) a = fmaf(t[k], linW[k * NC + tid], a);
        lg[tid] = a;
    }
    __syncthreads();
    if (tid == 0) {
        float mx = lg[0];
        for (int c = 1; c < NC; ++c) mx = fmaxf(mx, lg[c]);
        float se = 0.f;
        for (int c = 0; c < NC; ++c) se += expf(lg[c] - mx);
        lg[10] = mx + logf(se);
    }
    __syncthreads();
    if (tid < NC) out[g * NC + tid] = lg[tid] - lg[10];
}

// ---------------- host ----------------
extern "C" void kernel_launch(void* const* d_in, const int* in_sizes, int n_in,
                              void* d_out, int out_size, void* d_ws, size_t ws_size,
                              hipStream_t stream) {
    const float* x = (const float*)d_in[0];
    const int* edge = (const int*)d_in[1];
    const int* batch = (const int*)d_in[2];
    const float* convW1 = (const float*)d_in[3];
    const float* convb1 = (const float*)d_in[4];
    const float* convW2 = (const float*)d_in[5];
    const float* convb2 = (const float*)d_in[6];
    const float* convgamma = (const float*)d_in[7];
    const float* convbeta = (const float*)d_in[8];
    const float* fc1W = (const float*)d_in[9];
    const float* fc1b = (const float*)d_in[10];
    const float* fc1gamma = (const float*)d_in[11];
    const float* fc1beta = (const float*)d_in[12];
    const float* fc2W = (const float*)d_in[13];
    const float* fc2b = (const float*)d_in[14];
    const float* fc2gamma = (const float*)d_in[15];
    const float* fc2beta = (const float*)d_in[16];
    const float* linW = (const float*)d_in[17];
    const float* linb = (const float*)d_in[18];

    const int N = in_sizes[0] / D;
    const int E = in_sizes[1] / 2;
    const int* srcs = edge;
    const int* dsts = edge + E;
    const float invN = 1.f / (float)N;
    const int NBUK = (N + 15) >> 4;  // 16-node buckets

    char* p = (char*)d_ws;
    auto alloc = [&](size_t bytes) -> void* {
        void* r = (void*)p;
        p += (bytes + 255) & ~(size_t)255;
        return r;
    };
    uint* xb = (uint*)alloc((size_t)N * 64 * 4);   // bf16 x
    uint* zA = (uint*)alloc((size_t)N * 64 * 4);   // layer output ping
    uint* zB = (uint*)alloc((size_t)N * 64 * 4);   // layer output pong; aliases ebuf pre-loop
    ushort* wt = (ushort*)alloc((size_t)10 * D * D * 2);
    int* pad = (int*)alloc((size_t)N * PAD * 4);   // padded CSR
    int* cnt = (int*)alloc((size_t)N * 4);
    int* gstart = (int*)alloc((size_t)(NG + 1) * 4);
    int* bcnt = (int*)alloc((size_t)NBUK * 4);
    float* stats_all = (float*)alloc((size_t)5 * 2 * D * 4);
    float* pool = (float*)alloc((size_t)NG * D * 4);
    float* sqbuf = (float*)alloc((size_t)NG * D * 4);
    float* ybuf = (float*)alloc((size_t)NG * D * 4);
    float* gbuf = (float*)alloc((size_t)NG * D * 4);
    float* total = (float*)alloc((size_t)NG * D * 4);

    uint* ebuf = zB;  // NBUK*CAP*4 = 17.6 MB <= N*256B; consumed by csr_phaseB before layers run

    // ---- preprocessing ----
    zero_ints<<<(NBUK + 255) / 256, 256, 0, stream>>>(bcnt, NBUK);
    gstart_bsearch<<<3, 256, 0, stream>>>(batch, N, gstart);
    scatter_bucket<<<2048, 256, 0, stream>>>(srcs, dsts, E, bcnt, ebuf);
    cvt_bf16<<<2048, 256, 0, stream>>>(x, xb, N * 64);
    prep_w<<<10, 256, 0, stream>>>(convW1, convW2, wt);
    csr_phaseB<<<NBUK, 256, 0, stream>>>(ebuf, bcnt, cnt, pad, N);

    // ---- g0 path (exact fp32 pooling of x) ----
    pool_stats<0><<<NG, 256, 0, stream>>>(x, gstart, pool, nullptr);
    fc_forward<<<NG, D, 0, stream>>>(pool, nullptr, nullptr, nullptr, 0.f, nullptr, nullptr,
                                     fc1W, fc1b, ybuf);
    fc_bn2<<<D, 256, 0, stream>>>(ybuf, fc1gamma, fc1beta, gbuf, total, 1);

    // ---- 5 GIN layers (fused node path) ----
    const uint* src = xb;
    uint* dst = zA;
    const int fgrid = (N + 63) / 64;
    for (int i = 0; i < 5; ++i) {
        const float* st = (i == 0) ? nullptr : (stats_all + (size_t)(i - 1) * 2 * D);
        const float* ga = (i == 0) ? nullptr : (convgamma + (size_t)(i - 1) * D);
        const float* be = (i == 0) ? nullptr : (convbeta + (size_t)(i - 1) * D);
        gin_fused<<<fgrid, 256, 0, stream>>>((const uint4*)src, st, ga, be, invN, cnt, pad,
                                             wt + (size_t)i * D * D, convb1 + (size_t)i * D,
                                             wt + (size_t)(5 + i) * D * D, convb2 + (size_t)i * D,
                                             dst, N);
        float* st_i = stats_all + (size_t)i * 2 * D;
        pool_stats<1><<<NG, 256, 0, stream>>>(dst, gstart, pool, sqbuf);
        col_stats<<<D, 256, 0, stream>>>(pool, sqbuf, st_i);
        fc_forward<<<NG, D, 0, stream>>>(pool, st_i,
                                         convgamma + (size_t)i * D, convbeta + (size_t)i * D,
                                         invN, gstart, gbuf, fc2W, fc2b, ybuf);
        fc_bn2<<<D, 256, 0, stream>>>(ybuf, fc2gamma, fc2beta, gbuf, total, 0);
        src = dst;
        dst = (dst == zA) ? zB : zA;
    }

    // ---- classifier ----
    final_logits<<<NG, D, 0, stream>>>(total, linW, linb, (float*)d_out);
}